// Round 1
// baseline (165.900 us; speedup 1.0000x reference)
//
#include <hip/hip_runtime.h>

// 22-qubit QAOA state-vector simulation.
// state: float2 (re,im) per amplitude, N = 2^22 (32 MB in d_ws).
// Layer l: c *= exp(i*gamma[l]*h); then for each bit b: c[x] = cb*c[x] + i*sb*c[x^b].
// Per-qubit rotations within a layer commute -> reorder stages:
//   K1: init+phase1+layer1 low bits (0..12)
//   K2: layer1 high bits (13..21) + phase2 + layer2 high bits
//   K3: layer2 low bits + fused |c|^2 * hS partial reduction
//   K4: final reduce of 512 partials

#define NTOT    (1u << 22)
#define LO_BITS 13
#define HI_BITS 9
#define LO      (1u << LO_BITS)   // 8192
#define HI      (1u << HI_BITS)   // 512
#define GRP     16                // lo-columns per K2 block (128B coalescing)
#define TPB     512

// XOR swizzle: permute low 5 bits by bits 5..9 -> breaks power-of-2 bank aliasing
__device__ __forceinline__ unsigned swz(unsigned i) {
    return i ^ ((i >> 5) & 31u);
}

// K2 LDS address: column g (0..15), element hi (0..511); per-column XOR swizzle
__device__ __forceinline__ unsigned adr2(unsigned g, unsigned hi) {
    return (g << HI_BITS) | (hi ^ ((g << 1) & 31u));
}

#define BFLY(A0, A1, CB, SB) {              \
    unsigned _a0 = (A0), _a1 = (A1);        \
    float r0 = sR[_a0], m0 = sI[_a0];       \
    float r1 = sR[_a1], m1 = sI[_a1];       \
    sR[_a0] = (CB) * r0 - (SB) * m1;        \
    sI[_a0] = (CB) * m0 + (SB) * r1;        \
    sR[_a1] = (CB) * r1 - (SB) * m0;        \
    sI[_a1] = (CB) * m1 + (SB) * r0; }

// ---------------- K1: init + phase1 + layer-1 low stages ----------------
__global__ __launch_bounds__(TPB) void k_init_low(
    const float* __restrict__ h, const float* __restrict__ gam,
    const float* __restrict__ bet, float2* __restrict__ st)
{
    __shared__ float sR[LO];
    __shared__ float sI[LO];
    const float g1 = gam[0];
    const float cb = __cosf(bet[0]);
    const float sb = __sinf(bet[0]);
    const unsigned t = threadIdx.x;
    const size_t base = (size_t)blockIdx.x * LO;

    #pragma unroll
    for (int r = 0; r < LO / TPB; ++r) {
        unsigned i = t + r * TPB;
        float s, c;
        __sincosf(g1 * h[base + i], &s, &c);
        sR[swz(i)] = c * 0x1p-11f;   // 1/sqrt(2^22) = 2^-11 exactly
        sI[swz(i)] = s * 0x1p-11f;
    }
    for (int sg = 0; sg < LO_BITS; ++sg) {
        __syncthreads();
        const unsigned bit = 1u << sg;
        const unsigned msk = bit - 1u;
        #pragma unroll
        for (int k = 0; k < LO / (2 * TPB); ++k) {
            unsigned p  = t + k * TPB;
            unsigned i0 = ((p & ~msk) << 1) | (p & msk);
            BFLY(swz(i0), swz(i0 | bit), cb, sb);
        }
    }
    __syncthreads();
    #pragma unroll
    for (int r = 0; r < LO / TPB; ++r) {
        unsigned i = t + r * TPB;
        st[base + i] = make_float2(sR[swz(i)], sI[swz(i)]);
    }
}

// -------- K2: layer-1 high stages + phase2 + layer-2 high stages --------
__global__ __launch_bounds__(TPB) void k_high(
    const float* __restrict__ h, const float* __restrict__ gam,
    const float* __restrict__ bet, float2* __restrict__ st)
{
    __shared__ float sR[GRP * HI];
    __shared__ float sI[GRP * HI];
    const float g2  = gam[1];
    const float cb1 = __cosf(bet[0]), sb1 = __sinf(bet[0]);
    const float cb2 = __cosf(bet[1]), sb2 = __sinf(bet[1]);
    const unsigned t   = threadIdx.x;
    const unsigned lo0 = blockIdx.x * GRP;
    float hv[GRP * HI / TPB];   // 16 h values per thread, held across stages

    #pragma unroll
    for (int r = 0; r < GRP * HI / TPB; ++r) {
        unsigned lin = t + r * TPB;
        unsigned g   = lin & (GRP - 1);
        unsigned hi  = lin >> 4;
        size_t gi = (size_t)hi * LO + lo0 + g;
        float2 v = st[gi];                    // 16 consecutive float2 = 128B
        unsigned a = adr2(g, hi);
        sR[a] = v.x; sI[a] = v.y;
        hv[r] = h[gi];
    }
    // layer-1 high stages
    for (int sg = 0; sg < HI_BITS; ++sg) {
        __syncthreads();
        const unsigned bit = 1u << sg;
        const unsigned msk = bit - 1u;
        #pragma unroll
        for (int k = 0; k < GRP * HI / (2 * TPB); ++k) {
            unsigned pl = t + k * TPB;
            unsigned g  = pl & (GRP - 1);
            unsigned pp = pl >> 4;                       // 0..255
            unsigned i0 = ((pp & ~msk) << 1) | (pp & msk);
            BFLY(adr2(g, i0), adr2(g, i0 | bit), cb1, sb1);
        }
    }
    // phase2 (elementwise, after layer-1 mixing is complete for these elems)
    __syncthreads();
    #pragma unroll
    for (int r = 0; r < GRP * HI / TPB; ++r) {
        unsigned lin = t + r * TPB;
        unsigned g   = lin & (GRP - 1);
        unsigned hi  = lin >> 4;
        unsigned a = adr2(g, hi);
        float s, c;
        __sincosf(g2 * hv[r], &s, &c);
        float re = sR[a], im = sI[a];
        sR[a] = re * c - im * s;
        sI[a] = re * s + im * c;
    }
    // layer-2 high stages
    for (int sg = 0; sg < HI_BITS; ++sg) {
        __syncthreads();
        const unsigned bit = 1u << sg;
        const unsigned msk = bit - 1u;
        #pragma unroll
        for (int k = 0; k < GRP * HI / (2 * TPB); ++k) {
            unsigned pl = t + k * TPB;
            unsigned g  = pl & (GRP - 1);
            unsigned pp = pl >> 4;
            unsigned i0 = ((pp & ~msk) << 1) | (pp & msk);
            BFLY(adr2(g, i0), adr2(g, i0 | bit), cb2, sb2);
        }
    }
    __syncthreads();
    #pragma unroll
    for (int r = 0; r < GRP * HI / TPB; ++r) {
        unsigned lin = t + r * TPB;
        unsigned g   = lin & (GRP - 1);
        unsigned hi  = lin >> 4;
        unsigned a = adr2(g, hi);
        st[(size_t)hi * LO + lo0 + g] = make_float2(sR[a], sI[a]);
    }
}

// -------- K3: layer-2 low stages + fused |c|^2 * hS partial sums --------
__global__ __launch_bounds__(TPB) void k_low2(
    const float* __restrict__ hS, const float* __restrict__ bet,
    const float2* __restrict__ st, float* __restrict__ partial)
{
    __shared__ float sR[LO];
    __shared__ float sI[LO];
    const float cb = __cosf(bet[1]);
    const float sb = __sinf(bet[1]);
    const unsigned t = threadIdx.x;
    const size_t base = (size_t)blockIdx.x * LO;

    #pragma unroll
    for (int r = 0; r < LO / TPB; ++r) {
        unsigned i = t + r * TPB;
        float2 v = st[base + i];
        sR[swz(i)] = v.x; sI[swz(i)] = v.y;
    }
    for (int sg = 0; sg < LO_BITS; ++sg) {
        __syncthreads();
        const unsigned bit = 1u << sg;
        const unsigned msk = bit - 1u;
        #pragma unroll
        for (int k = 0; k < LO / (2 * TPB); ++k) {
            unsigned p  = t + k * TPB;
            unsigned i0 = ((p & ~msk) << 1) | (p & msk);
            BFLY(swz(i0), swz(i0 | bit), cb, sb);
        }
    }
    __syncthreads();
    float acc = 0.f;
    #pragma unroll
    for (int r = 0; r < LO / TPB; ++r) {
        unsigned i = t + r * TPB;
        float re = sR[swz(i)], im = sI[swz(i)];
        acc = fmaf(re * re + im * im, hS[base + i], acc);
    }
    // wave reduce (64 lanes)
    #pragma unroll
    for (int off = 32; off >= 1; off >>= 1)
        acc += __shfl_down(acc, off, 64);
    __syncthreads();                 // all LDS reads done; reuse sR for wave sums
    if ((t & 63u) == 0u) sR[t >> 6] = acc;
    __syncthreads();
    if (t == 0) {
        float s = 0.f;
        #pragma unroll
        for (int w = 0; w < TPB / 64; ++w) s += sR[w];
        partial[blockIdx.x] = s;
    }
}

// ---------------- K4: final reduce of 512 partials ----------------
__global__ __launch_bounds__(TPB) void k_final(
    const float* __restrict__ partial, float* __restrict__ out)
{
    __shared__ float wsum[TPB / 64];
    const unsigned t = threadIdx.x;
    float acc = partial[t];          // grid of K3 = 512 = TPB
    #pragma unroll
    for (int off = 32; off >= 1; off >>= 1)
        acc += __shfl_down(acc, off, 64);
    if ((t & 63u) == 0u) wsum[t >> 6] = acc;
    __syncthreads();
    if (t == 0) {
        float s = 0.f;
        #pragma unroll
        for (int w = 0; w < TPB / 64; ++w) s += wsum[w];
        out[0] = s;
    }
}

extern "C" void kernel_launch(void* const* d_in, const int* in_sizes, int n_in,
                              void* d_out, int out_size, void* d_ws, size_t ws_size,
                              hipStream_t stream)
{
    (void)in_sizes; (void)n_in; (void)out_size; (void)ws_size;
    const float* h   = (const float*)d_in[0];
    const float* hS  = (const float*)d_in[1];
    const float* gam = (const float*)d_in[2];
    const float* bet = (const float*)d_in[3];
    float2* st      = (float2*)d_ws;                                    // 32 MB state
    float* partial  = (float*)((char*)d_ws + (size_t)NTOT * sizeof(float2));
    float* out      = (float*)d_out;

    k_init_low<<<dim3(NTOT / LO), dim3(TPB), 0, stream>>>(h, gam, bet, st);
    k_high   <<<dim3(LO / GRP),   dim3(TPB), 0, stream>>>(h, gam, bet, st);
    k_low2   <<<dim3(NTOT / LO),  dim3(TPB), 0, stream>>>(hS, bet, st, partial);
    k_final  <<<dim3(1),          dim3(TPB), 0, stream>>>(partial, out);
}

// Round 2
// 124.851 us; speedup vs baseline: 1.3288x; 1.3288x over previous
//
#include <hip/hip_runtime.h>

// 22-qubit QAOA state-vector simulation, register/shfl/transpose butterflies.
// Butterfly c[x] = cb*c[x] + i*sb*c[x^bit] is SYMMETRIC: every element's update
// is cb*self + i*sb*partner. So each stage runs where the partner lives:
//   register bits -> pure FMAs; lane bits -> __shfl_xor; wave bits -> one LDS
//   transpose swaps wave-bits into register position, then FMAs.
// Pass split: K1 bits 0-12 (layer1), K2 bits 13-21 (layer1+phase2+layer2),
// K3 bits 0-12 (layer2) + fused |c|^2*hS reduction, K4 final reduce.

#define NTOT    (1u << 22)
#define LO_BITS 13
#define HI_BITS 9
#define LO      (1u << LO_BITS)   // 8192
#define HI      (1u << HI_BITS)   // 512
#define GRP     16                // lo-columns per K2 block (128B segments)
#define TPB     512
#define R       16                // complex elements per thread

// pairwise register butterfly on register-index bit MASK
#define REGSTAGE(MASK, CB, SB) {                                  \
    _Pragma("unroll")                                             \
    for (int r0 = 0; r0 < R; ++r0) {                              \
        if ((r0 & (MASK)) == 0) {                                 \
            const int r1 = r0 | (MASK);                           \
            float t0r = re[r0], t0i = im[r0];                     \
            float t1r = re[r1], t1i = im[r1];                     \
            re[r0] = (CB) * t0r - (SB) * t1i;                     \
            im[r0] = (CB) * t0i + (SB) * t1r;                     \
            re[r1] = (CB) * t1r - (SB) * t0i;                     \
            im[r1] = (CB) * t1i + (SB) * t0r;                     \
        } } }

// cross-lane butterfly on lane-index bit MASK (no barrier needed)
#define SHFLSTAGE(MASK, CB, SB) {                                 \
    _Pragma("unroll")                                             \
    for (int r = 0; r < R; ++r) {                                 \
        float tr = re[r], ti = im[r];                             \
        float pr = __shfl_xor(tr, (MASK), 64);                    \
        float pi = __shfl_xor(ti, (MASK), 64);                    \
        re[r] = (CB) * tr - (SB) * pi;                            \
        im[r] = (CB) * ti + (SB) * pr;                            \
    } }

// ---------------- K1: init + phase1 + layer-1 bits 0-12 ----------------
__global__ __launch_bounds__(TPB, 4) void k_init_low(
    const float* __restrict__ h, const float* __restrict__ gam,
    const float* __restrict__ bet, float2* __restrict__ st)
{
    __shared__ float2 sC[LO];
    const float g1 = gam[0];
    const float cb = __cosf(bet[0]), sb = __sinf(bet[0]);
    const unsigned t = threadIdx.x, lane = t & 63u, wave = t >> 6;
    const size_t base = (size_t)blockIdx.x * LO;
    float re[R], im[R];

    // element i = r*512 + t : i[5:0]=lane, i[8:6]=wave, i[12:9]=r
    #pragma unroll
    for (int r = 0; r < R; ++r) {
        float s, c;
        __sincosf(g1 * h[base + (unsigned)r * TPB + t], &s, &c);
        re[r] = c * 0x1p-11f;   // 1/sqrt(2^22)
        im[r] = s * 0x1p-11f;
    }
    REGSTAGE(1, cb, sb)  REGSTAGE(2, cb, sb)      // bits 9,10
    REGSTAGE(4, cb, sb)  REGSTAGE(8, cb, sb)      // bits 11,12
    SHFLSTAGE(1,  cb, sb) SHFLSTAGE(2,  cb, sb)   // bits 0,1
    SHFLSTAGE(4,  cb, sb) SHFLSTAGE(8,  cb, sb)   // bits 2,3
    SHFLSTAGE(16, cb, sb) SHFLSTAGE(32, cb, sb)   // bits 4,5
    // transpose: bring bits 6-8 (wave) into register position
    #pragma unroll
    for (int r = 0; r < R; ++r) sC[(unsigned)r * TPB + t] = make_float2(re[r], im[r]);
    __syncthreads();
    #pragma unroll
    for (int r = 0; r < R; ++r) {
        unsigned j = lane | ((unsigned)(r & 7) << 6) | (wave << 9) | ((unsigned)(r >> 3) << 12);
        float2 v = sC[j]; re[r] = v.x; im[r] = v.y;
    }
    REGSTAGE(1, cb, sb)  REGSTAGE(2, cb, sb)      // bits 6,7
    REGSTAGE(4, cb, sb)                           // bit 8
    #pragma unroll
    for (int r = 0; r < R; ++r) {
        unsigned j = lane | ((unsigned)(r & 7) << 6) | (wave << 9) | ((unsigned)(r >> 3) << 12);
        st[base + j] = make_float2(re[r], im[r]);
    }
}

// -------- K2: layer-1 bits 13-21 + phase2 + layer-2 bits 13-21 --------
__global__ __launch_bounds__(TPB, 4) void k_high(
    const float* __restrict__ h, const float* __restrict__ gam,
    const float* __restrict__ bet, float2* __restrict__ st)
{
    __shared__ float2 sC[GRP * HI];   // 8192
    const float g2  = gam[1];
    const float cb1 = __cosf(bet[0]), sb1 = __sinf(bet[0]);
    const float cb2 = __cosf(bet[1]), sb2 = __sinf(bet[1]);
    const unsigned t = threadIdx.x, lane = t & 63u, wave = t >> 6;
    const unsigned lo0 = blockIdx.x * GRP;
    const unsigned g   = lane & (GRP - 1);   // lo offset (coalescing)
    const unsigned h01 = lane >> 4;          // hi bits 0-1
    float re[R], im[R];

    // mapping A: hi = h01 | wave<<2 | r<<5
    #pragma unroll
    for (int r = 0; r < R; ++r) {
        unsigned hi = h01 | (wave << 2) | ((unsigned)r << 5);
        float2 v = st[(size_t)hi * LO + lo0 + g];
        re[r] = v.x; im[r] = v.y;
    }
    // layer1: hi bits 5-8 (reg), hi bits 0-1 (lane bits 4,5)
    REGSTAGE(1, cb1, sb1)  REGSTAGE(2, cb1, sb1)
    REGSTAGE(4, cb1, sb1)  REGSTAGE(8, cb1, sb1)
    SHFLSTAGE(16, cb1, sb1) SHFLSTAGE(32, cb1, sb1)
    // transpose A->B: B has hi = h01 | (r&7)<<2 | wave<<5 | (r>>3)<<8
    #pragma unroll
    for (int r = 0; r < R; ++r) {
        unsigned li = g | (h01 << 4) | (wave << 6) | ((unsigned)r << 9);
        sC[li] = make_float2(re[r], im[r]);
    }
    __syncthreads();
    #pragma unroll
    for (int r = 0; r < R; ++r) {
        unsigned li = g | (h01 << 4) | ((unsigned)(r & 7) << 6) | (wave << 9) | ((unsigned)(r >> 3) << 12);
        float2 v = sC[li]; re[r] = v.x; im[r] = v.y;
    }
    REGSTAGE(1, cb1, sb1)  REGSTAGE(2, cb1, sb1)  REGSTAGE(4, cb1, sb1)  // hi bits 2,3,4
    // phase2 (layer-1 now complete for these elements; low bits done in K1)
    #pragma unroll
    for (int r = 0; r < R; ++r) {
        unsigned hi = h01 | ((unsigned)(r & 7) << 2) | (wave << 5) | ((unsigned)(r >> 3) << 8);
        float s, c;
        __sincosf(g2 * h[(size_t)hi * LO + lo0 + g], &s, &c);
        float tr = re[r], ti = im[r];
        re[r] = tr * c - ti * s;
        im[r] = tr * s + ti * c;
    }
    // layer2 at B: hi bits 2,3,4 (reg 1,2,4), hi bit 8 (reg 8), hi bits 0,1 (lane)
    REGSTAGE(1, cb2, sb2)  REGSTAGE(2, cb2, sb2)
    REGSTAGE(4, cb2, sb2)  REGSTAGE(8, cb2, sb2)
    SHFLSTAGE(16, cb2, sb2) SHFLSTAGE(32, cb2, sb2)
    // transpose B->A, then hi bits 5,6,7 (reg)
    __syncthreads();
    #pragma unroll
    for (int r = 0; r < R; ++r) {
        unsigned li = g | (h01 << 4) | ((unsigned)(r & 7) << 6) | (wave << 9) | ((unsigned)(r >> 3) << 12);
        sC[li] = make_float2(re[r], im[r]);
    }
    __syncthreads();
    #pragma unroll
    for (int r = 0; r < R; ++r) {
        unsigned li = g | (h01 << 4) | (wave << 6) | ((unsigned)r << 9);
        float2 v = sC[li]; re[r] = v.x; im[r] = v.y;
    }
    REGSTAGE(1, cb2, sb2)  REGSTAGE(2, cb2, sb2)  REGSTAGE(4, cb2, sb2)  // hi bits 5,6,7
    #pragma unroll
    for (int r = 0; r < R; ++r) {
        unsigned hi = h01 | (wave << 2) | ((unsigned)r << 5);
        st[(size_t)hi * LO + lo0 + g] = make_float2(re[r], im[r]);
    }
}

// -------- K3: layer-2 bits 0-12 + fused |c|^2 * hS partial sums --------
__global__ __launch_bounds__(TPB, 4) void k_low2(
    const float* __restrict__ hS, const float* __restrict__ bet,
    const float2* __restrict__ st, float* __restrict__ partial)
{
    __shared__ float2 sC[LO];
    __shared__ float wsum[TPB / 64];
    const float cb = __cosf(bet[1]), sb = __sinf(bet[1]);
    const unsigned t = threadIdx.x, lane = t & 63u, wave = t >> 6;
    const size_t base = (size_t)blockIdx.x * LO;
    float re[R], im[R];

    #pragma unroll
    for (int r = 0; r < R; ++r) {
        float2 v = st[base + (unsigned)r * TPB + t];
        re[r] = v.x; im[r] = v.y;
    }
    REGSTAGE(1, cb, sb)  REGSTAGE(2, cb, sb)
    REGSTAGE(4, cb, sb)  REGSTAGE(8, cb, sb)
    SHFLSTAGE(1,  cb, sb) SHFLSTAGE(2,  cb, sb)
    SHFLSTAGE(4,  cb, sb) SHFLSTAGE(8,  cb, sb)
    SHFLSTAGE(16, cb, sb) SHFLSTAGE(32, cb, sb)
    #pragma unroll
    for (int r = 0; r < R; ++r) sC[(unsigned)r * TPB + t] = make_float2(re[r], im[r]);
    __syncthreads();
    #pragma unroll
    for (int r = 0; r < R; ++r) {
        unsigned j = lane | ((unsigned)(r & 7) << 6) | (wave << 9) | ((unsigned)(r >> 3) << 12);
        float2 v = sC[j]; re[r] = v.x; im[r] = v.y;
    }
    REGSTAGE(1, cb, sb)  REGSTAGE(2, cb, sb)  REGSTAGE(4, cb, sb)
    float acc = 0.f;
    #pragma unroll
    for (int r = 0; r < R; ++r) {
        unsigned j = lane | ((unsigned)(r & 7) << 6) | (wave << 9) | ((unsigned)(r >> 3) << 12);
        acc = fmaf(re[r] * re[r] + im[r] * im[r], hS[base + j], acc);
    }
    #pragma unroll
    for (int off = 32; off >= 1; off >>= 1)
        acc += __shfl_down(acc, off, 64);
    if (lane == 0) wsum[wave] = acc;
    __syncthreads();
    if (t == 0) {
        float s = 0.f;
        #pragma unroll
        for (int w = 0; w < TPB / 64; ++w) s += wsum[w];
        partial[blockIdx.x] = s;
    }
}

// ---------------- K4: final reduce of 512 partials ----------------
__global__ __launch_bounds__(TPB) void k_final(
    const float* __restrict__ partial, float* __restrict__ out)
{
    __shared__ float wsum[TPB / 64];
    const unsigned t = threadIdx.x;
    float acc = partial[t];
    #pragma unroll
    for (int off = 32; off >= 1; off >>= 1)
        acc += __shfl_down(acc, off, 64);
    if ((t & 63u) == 0u) wsum[t >> 6] = acc;
    __syncthreads();
    if (t == 0) {
        float s = 0.f;
        #pragma unroll
        for (int w = 0; w < TPB / 64; ++w) s += wsum[w];
        out[0] = s;
    }
}

extern "C" void kernel_launch(void* const* d_in, const int* in_sizes, int n_in,
                              void* d_out, int out_size, void* d_ws, size_t ws_size,
                              hipStream_t stream)
{
    (void)in_sizes; (void)n_in; (void)out_size; (void)ws_size;
    const float* h   = (const float*)d_in[0];
    const float* hS  = (const float*)d_in[1];
    const float* gam = (const float*)d_in[2];
    const float* bet = (const float*)d_in[3];
    float2* st     = (float2*)d_ws;                                   // 32 MB state
    float* partial = (float*)((char*)d_ws + (size_t)NTOT * sizeof(float2));
    float* out     = (float*)d_out;

    k_init_low<<<dim3(NTOT / LO), dim3(TPB), 0, stream>>>(h, gam, bet, st);
    k_high    <<<dim3(LO / GRP),  dim3(TPB), 0, stream>>>(h, gam, bet, st);
    k_low2    <<<dim3(NTOT / LO), dim3(TPB), 0, stream>>>(hS, bet, st, partial);
    k_final   <<<dim3(1),         dim3(TPB), 0, stream>>>(partial, out);
}